// Round 1
// baseline (358.393 us; speedup 1.0000x reference)
//
#include <hip/hip_runtime.h>
#include <math.h>

#define NB 4
#define HID 4096
#define CKV 512
#define CQ 1536
#define NH 32
#define HD 128
#define RD 64
#define SS 4096
#define SK 4097

#define SCALE_F 0.07216878364870322f  // 1/sqrt(192)

// workspace offsets (floats)
enum : int {
  WS_CKV    = 0,                       // [NB][CKV]      (zeroed, atomic)
  WS_CQ     = WS_CKV + NB*CKV,         // [NB][CQ]       (zeroed, atomic)
  WS_KRRAW  = WS_CQ + NB*CQ,           // [NB][RD]       (zeroed, atomic)
  WS_QC     = WS_KRRAW + NB*RD,        // [NB][HID]      (zeroed, atomic)
  WS_QRRAW  = WS_QC + NB*HID,          // [NB][NH*RD]    (zeroed, atomic)
  WS_OLAT   = WS_QRRAW + NB*NH*RD,     // [NB][NH][CKV]  (zeroed, atomic)
  WS_ATTN   = WS_OLAT + NB*NH*CKV,     // [NB][HID]      (zeroed, atomic)
  WS_ZERO_N = WS_ATTN + NB*HID,        // = 114944
  WS_QABS   = WS_ZERO_N,               // [NB][NH][CKV]
  WS_QROPE  = WS_QABS + NB*NH*CKV,     // [NB][NH][RD]
  WS_KROPE  = WS_QROPE + NB*NH*RD,     // [NB][RD]
  WS_SCORES = WS_KROPE + NB*RD,        // [NB][NH][SK]
  WS_TOTAL  = WS_SCORES + NB*NH*SK     // 713344 floats = 2.85 MB
};

__device__ inline void fma4(float4& a, float s, const float4& v) {
  a.x += s*v.x; a.y += s*v.y; a.z += s*v.z; a.w += s*v.w;
}

// ---------------- K1: hidden -> c_KV, c_Q, k_R_raw (K-split 32, atomics) ---
__global__ __launch_bounds__(256)
void k_proj1(const float* __restrict__ hidden,
             const float* __restrict__ Wdkv,
             const float* __restrict__ Wdq,
             const float* __restrict__ Wkr,
             float* __restrict__ ws) {
  __shared__ float hid_s[NB][128];
  const int tid = threadIdx.x;
  const int k0 = blockIdx.y * 128;
  for (int e = tid; e < NB*128; e += 256) {
    int b = e >> 7, i = e & 127;
    hid_s[b][i] = hidden[b*HID + k0 + i];
  }
  __syncthreads();
  const int col = blockIdx.x * 256 + tid;
  const float* W; int C; float* dst; int wcol;
  if (col < 512)       { W = Wdkv; C = CKV; wcol = col;        dst = ws + WS_CKV; }
  else if (col < 2048) { W = Wdq;  C = CQ;  wcol = col - 512;  dst = ws + WS_CQ; }
  else if (col < 2112) { W = Wkr;  C = RD;  wcol = col - 2048; dst = ws + WS_KRRAW; }
  else return;
  float a0=0,a1=0,a2=0,a3=0;
  const float* wp = W + (size_t)k0 * C + wcol;
  #pragma unroll 4
  for (int i = 0; i < 128; ++i) {
    float w = wp[(size_t)i * C];
    a0 += hid_s[0][i] * w;
    a1 += hid_s[1][i] * w;
    a2 += hid_s[2][i] * w;
    a3 += hid_s[3][i] * w;
  }
  atomicAdd(&dst[0*C + wcol], a0);
  atomicAdd(&dst[1*C + wcol], a1);
  atomicAdd(&dst[2*C + wcol], a2);
  atomicAdd(&dst[3*C + wcol], a3);
}

// ---------------- K2: c_Q -> q_C, q_R_raw (K-split 12, atomics) ------------
__global__ __launch_bounds__(256)
void k_proj2(const float* __restrict__ Wuq,
             const float* __restrict__ Wqr,
             float* __restrict__ ws) {
  __shared__ float cq_s[NB][128];
  const int tid = threadIdx.x;
  const int k0 = blockIdx.y * 128;
  for (int e = tid; e < NB*128; e += 256) {
    int b = e >> 7, i = e & 127;
    cq_s[b][i] = ws[WS_CQ + b*CQ + k0 + i];
  }
  __syncthreads();
  const int col = blockIdx.x * 256 + tid;  // < 6144 always
  const float* W; int C; float* dst; int wcol;
  if (col < 4096) { W = Wuq; C = NH*HD; wcol = col;        dst = ws + WS_QC; }
  else            { W = Wqr; C = NH*RD; wcol = col - 4096; dst = ws + WS_QRRAW; }
  float a0=0,a1=0,a2=0,a3=0;
  const float* wp = W + (size_t)k0 * C + wcol;
  #pragma unroll 4
  for (int i = 0; i < 128; ++i) {
    float w = wp[(size_t)i * C];
    a0 += cq_s[0][i] * w;
    a1 += cq_s[1][i] * w;
    a2 += cq_s[2][i] * w;
    a3 += cq_s[3][i] * w;
  }
  atomicAdd(&dst[0*C + wcol], a0);
  atomicAdd(&dst[1*C + wcol], a1);
  atomicAdd(&dst[2*C + wcol], a2);
  atomicAdd(&dst[3*C + wcol], a3);
}

// -------- K3: q_abs = q_C @ W_UK^T per head; RoPE q_R,k_R; new cache rows --
__global__ __launch_bounds__(256)
void k_absorb_rope(const float* __restrict__ Wuk,
                   float* __restrict__ ws,
                   float* __restrict__ out_ckv,
                   float* __restrict__ out_kr) {
  const int bid = blockIdx.x, tid = threadIdx.x;
  if (bid < 128) {
    const int h = bid >> 2, cq = bid & 3;
    __shared__ float qc_s[NB][HD];
    __shared__ float part_s[NB][256];
    for (int e = tid; e < NB*HD; e += 256) {
      int b = e >> 7, d = e & 127;
      qc_s[b][d] = ws[WS_QC + b*HID + h*HD + d];
    }
    __syncthreads();
    const int c = cq*128 + (tid & 127);
    const int dh = (tid >> 7) * 64;
    const float4* wrow = (const float4*)(Wuk + (size_t)c*(NH*HD) + h*HD + dh);
    float acc[NB] = {0,0,0,0};
    #pragma unroll
    for (int d4 = 0; d4 < 16; ++d4) {
      float4 w4 = wrow[d4];
      #pragma unroll
      for (int b = 0; b < NB; ++b) {
        float4 q4 = *(const float4*)&qc_s[b][dh + d4*4];
        acc[b] += w4.x*q4.x + w4.y*q4.y + w4.z*q4.z + w4.w*q4.w;
      }
    }
    #pragma unroll
    for (int b = 0; b < NB; ++b) part_s[b][tid] = acc[b];
    __syncthreads();
    if (tid < 128) {
      #pragma unroll
      for (int b = 0; b < NB; ++b) {
        float v = part_s[b][tid] + part_s[b][tid + 128];
        ws[WS_QABS + (b*NH + h)*CKV + c] = v;
      }
    }
  } else {
    const double LN1E4 = 9.210340371976184;  // ln(10000)
    // q_R rope: NB*NH*32 pairs
    for (int pid = tid; pid < NB*NH*32; pid += 256) {
      int b = pid >> 10, rem = pid & 1023, h = rem >> 5, i = rem & 31;
      double ang = 4096.0 * exp(-(double)i / 32.0 * LN1E4);
      float cs = (float)cos(ang), sn = (float)sin(ang);
      float x1 = ws[WS_QRRAW + b*(NH*RD) + h*RD + 2*i];
      float x2 = ws[WS_QRRAW + b*(NH*RD) + h*RD + 2*i + 1];
      ws[WS_QROPE + (b*NH + h)*RD + 2*i]     = x1*cs - x2*sn;
      ws[WS_QROPE + (b*NH + h)*RD + 2*i + 1] = x1*sn + x2*cs;
    }
    // k_R rope + new k_R cache row
    if (tid < NB*32) {
      int b = tid >> 5, i = tid & 31;
      double ang = 4096.0 * exp(-(double)i / 32.0 * LN1E4);
      float cs = (float)cos(ang), sn = (float)sin(ang);
      float x1 = ws[WS_KRRAW + b*RD + 2*i];
      float x2 = ws[WS_KRRAW + b*RD + 2*i + 1];
      float o0 = x1*cs - x2*sn, o1 = x1*sn + x2*cs;
      ws[WS_KROPE + b*RD + 2*i]     = o0;
      ws[WS_KROPE + b*RD + 2*i + 1] = o1;
      out_kr[(size_t)b*SK*RD + (size_t)SS*RD + 2*i]     = o0;
      out_kr[(size_t)b*SK*RD + (size_t)SS*RD + 2*i + 1] = o1;
    }
    // new c_KV cache row
    for (int e = tid; e < NB*CKV; e += 256) {
      int b = e >> 9, cc = e & 511;
      out_ckv[(size_t)b*SK*CKV + (size_t)SS*CKV + cc] = ws[WS_CKV + b*CKV + cc];
    }
  }
}

// ---------------- K4: scores (absorbed) + mask, [B][NH][SK] ----------------
#define QAB_STRIDE 516
#define QR_STRIDE  68
__global__ __launch_bounds__(256)
void k_scores(const float* __restrict__ kv_cache,
              const float* __restrict__ kr_cache,
              const float* __restrict__ mask,
              float* __restrict__ ws) {
  extern __shared__ float sm[];
  float* qab_s = sm;                 // [32][516]
  float* qr_s  = sm + NH*QAB_STRIDE; // [32][68]
  const int tid = threadIdx.x;
  const int b = blockIdx.y;
  const int k0 = blockIdx.x * 128;
  for (int e = tid; e < NH*CKV/4; e += 256) {
    int h = e >> 7, c4 = e & 127;
    float4 v = ((const float4*)(ws + WS_QABS + (size_t)(b*NH + h)*CKV))[c4];
    *(float4*)&qab_s[h*QAB_STRIDE + c4*4] = v;
  }
  for (int e = tid; e < NH*RD/4; e += 256) {
    int h = e >> 4, r4 = e & 15;
    float4 v = ((const float4*)(ws + WS_QROPE + (size_t)(b*NH + h)*RD))[r4];
    *(float4*)&qr_s[h*QR_STRIDE + r4*4] = v;
  }
  __syncthreads();
  const int kt = tid & 15;
  const int h0 = (tid >> 4) * 2;
  const float4* ckv_row[8];
  const float4* kr_row[8];
  int kk[8];
  #pragma unroll
  for (int j = 0; j < 8; ++j) {
    int k = k0 + kt + j*16;
    kk[j] = k;
    if (k < SS) {
      ckv_row[j] = (const float4*)(kv_cache + ((size_t)b*SS + k)*CKV);
      kr_row[j]  = (const float4*)(kr_cache + ((size_t)b*SS + k)*RD);
    } else if (k == SS) {
      ckv_row[j] = (const float4*)(ws + WS_CKV + b*CKV);
      kr_row[j]  = (const float4*)(ws + WS_KROPE + b*RD);
    } else {  // dummy valid memory; store is guarded
      ckv_row[j] = (const float4*)(ws + WS_CKV);
      kr_row[j]  = (const float4*)(ws + WS_KROPE);
    }
  }
  float acc[2][8];
  #pragma unroll
  for (int i = 0; i < 2; ++i)
    #pragma unroll
    for (int j = 0; j < 8; ++j) acc[i][j] = 0.f;

  for (int c4 = 0; c4 < CKV/4; ++c4) {
    float4 cv[8];
    #pragma unroll
    for (int j = 0; j < 8; ++j) cv[j] = ckv_row[j][c4];
    #pragma unroll
    for (int i = 0; i < 2; ++i) {
      float4 q4 = *(const float4*)&qab_s[(h0+i)*QAB_STRIDE + c4*4];
      #pragma unroll
      for (int j = 0; j < 8; ++j)
        acc[i][j] += q4.x*cv[j].x + q4.y*cv[j].y + q4.z*cv[j].z + q4.w*cv[j].w;
    }
  }
  #pragma unroll
  for (int r4 = 0; r4 < RD/4; ++r4) {
    float4 cv[8];
    #pragma unroll
    for (int j = 0; j < 8; ++j) cv[j] = kr_row[j][r4];
    #pragma unroll
    for (int i = 0; i < 2; ++i) {
      float4 q4 = *(const float4*)&qr_s[(h0+i)*QR_STRIDE + r4*4];
      #pragma unroll
      for (int j = 0; j < 8; ++j)
        acc[i][j] += q4.x*cv[j].x + q4.y*cv[j].y + q4.z*cv[j].z + q4.w*cv[j].w;
    }
  }
  #pragma unroll
  for (int i = 0; i < 2; ++i)
    #pragma unroll
    for (int j = 0; j < 8; ++j) {
      int k = kk[j];
      if (k <= SS)
        ws[WS_SCORES + (size_t)(b*NH + h0 + i)*SK + k] =
            acc[i][j] * SCALE_F + mask[b*SK + k] * (-1e9f);
    }
}

// ---------------- K5: row softmax over SK=4097 ------------------------------
__global__ __launch_bounds__(256)
void k_softmax(float* __restrict__ ws) {
  __shared__ float red[256];
  const int tid = threadIdx.x;
  float* s = ws + WS_SCORES + (size_t)blockIdx.x * SK;
  float v[17];
  float m = -INFINITY;
  #pragma unroll
  for (int r = 0; r < 17; ++r) {
    int k = tid + r*256;
    v[r] = (k < SK) ? s[k] : -INFINITY;
    m = fmaxf(m, v[r]);
  }
  red[tid] = m; __syncthreads();
  for (int st = 128; st > 0; st >>= 1) {
    if (tid < st) red[tid] = fmaxf(red[tid], red[tid+st]);
    __syncthreads();
  }
  m = red[0]; __syncthreads();
  float e[17];
  float l = 0.f;
  #pragma unroll
  for (int r = 0; r < 17; ++r) {
    int k = tid + r*256;
    e[r] = (k < SK) ? __expf(v[r] - m) : 0.f;
    l += e[r];
  }
  red[tid] = l; __syncthreads();
  for (int st = 128; st > 0; st >>= 1) {
    if (tid < st) red[tid] += red[tid+st];
    __syncthreads();
  }
  float inv = 1.f / red[0];
  #pragma unroll
  for (int r = 0; r < 17; ++r) {
    int k = tid + r*256;
    if (k < SK) s[k] = e[r] * inv;
  }
}

// ---------------- K6: o_latent = probs @ c_KV (K-split, atomics) ------------
__global__ __launch_bounds__(256)
void k_pv(const float* __restrict__ kv_cache,
          float* __restrict__ ws) {
  __shared__ float pl[NH][128];
  const int tid = threadIdx.x;
  const int b = blockIdx.y;
  const int k0 = blockIdx.x * 128;
  for (int e = tid; e < NH*128; e += 256) {
    int h = e >> 7, kk = e & 127;
    int k = k0 + kk;
    pl[h][kk] = (k < SK) ? ws[WS_SCORES + (size_t)(b*NH + h)*SK + k] : 0.f;
  }
  __syncthreads();
  const int cg = tid & 63;     // c = cg*8 .. cg*8+7
  const int hg = tid >> 6;     // 0..3 ; heads h = hg + 4*i (uniform per wave)
  const int c = cg * 8;
  float4 acc[8][2];
  #pragma unroll
  for (int i = 0; i < 8; ++i) { acc[i][0] = make_float4(0,0,0,0); acc[i][1] = make_float4(0,0,0,0); }

  for (int kk = 0; kk < 128; kk += 4) {
    float4 cva[4], cvb[4];
    #pragma unroll
    for (int j = 0; j < 4; ++j) {
      int k = k0 + kk + j;
      const float* row = (k < SS) ? (kv_cache + ((size_t)b*SS + k)*CKV)
                       : (k == SS) ? (ws + WS_CKV + b*CKV)
                                   : (ws + WS_CKV);  // dummy; p==0 there
      cva[j] = *(const float4*)(row + c);
      cvb[j] = *(const float4*)(row + c + 4);
    }
    #pragma unroll
    for (int i = 0; i < 8; ++i) {
      int h = hg + 4*i;
      float4 p4 = *(const float4*)&pl[h][kk];
      fma4(acc[i][0], p4.x, cva[0]); fma4(acc[i][1], p4.x, cvb[0]);
      fma4(acc[i][0], p4.y, cva[1]); fma4(acc[i][1], p4.y, cvb[1]);
      fma4(acc[i][0], p4.z, cva[2]); fma4(acc[i][1], p4.z, cvb[2]);
      fma4(acc[i][0], p4.w, cva[3]); fma4(acc[i][1], p4.w, cvb[3]);
    }
  }
  #pragma unroll
  for (int i = 0; i < 8; ++i) {
    int h = hg + 4*i;
    float* dst = ws + WS_OLAT + (size_t)(b*NH + h)*CKV + c;
    atomicAdd(dst + 0, acc[i][0].x); atomicAdd(dst + 1, acc[i][0].y);
    atomicAdd(dst + 2, acc[i][0].z); atomicAdd(dst + 3, acc[i][0].w);
    atomicAdd(dst + 4, acc[i][1].x); atomicAdd(dst + 5, acc[i][1].y);
    atomicAdd(dst + 6, acc[i][1].z); atomicAdd(dst + 7, acc[i][1].w);
  }
}

// ---------------- K7: attn = o_latent @ W_UV (per head) ---------------------
__global__ __launch_bounds__(256)
void k_uv(const float* __restrict__ Wuv, float* __restrict__ ws) {
  __shared__ float ol_s[2][NB][64];
  const int tid = threadIdx.x;
  const int c0 = blockIdx.y * 64;
  const int colbase = blockIdx.x * 256;
  for (int e = tid; e < 2*NB*64; e += 256) {
    int hh = e >> 8, rem = e & 255, b = rem >> 6, cc = rem & 63;
    int h = (colbase >> 7) + hh;
    ol_s[hh][b][cc] = ws[WS_OLAT + (size_t)(b*NH + h)*CKV + c0 + cc];
  }
  __syncthreads();
  const int col = colbase + tid;
  const int hh = tid >> 7;
  float a0=0,a1=0,a2=0,a3=0;
  const float* wp = Wuv + (size_t)c0 * (NH*HD) + col;
  #pragma unroll 4
  for (int cc = 0; cc < 64; ++cc) {
    float w = wp[(size_t)cc * (NH*HD)];
    a0 += ol_s[hh][0][cc] * w;
    a1 += ol_s[hh][1][cc] * w;
    a2 += ol_s[hh][2][cc] * w;
    a3 += ol_s[hh][3][cc] * w;
  }
  atomicAdd(&ws[WS_ATTN + 0*HID + col], a0);
  atomicAdd(&ws[WS_ATTN + 1*HID + col], a1);
  atomicAdd(&ws[WS_ATTN + 2*HID + col], a2);
  atomicAdd(&ws[WS_ATTN + 3*HID + col], a3);
}

// ---------------- K8: out = attn @ W_O (K-split 32, atomics into d_out) -----
__global__ __launch_bounds__(256)
void k_wo(const float* __restrict__ Wo, const float* __restrict__ ws,
          float* __restrict__ out) {
  __shared__ float at_s[NB][128];
  const int tid = threadIdx.x;
  const int k0 = blockIdx.y * 128;
  for (int e = tid; e < NB*128; e += 256) {
    int b = e >> 7, i = e & 127;
    at_s[b][i] = ws[WS_ATTN + b*HID + k0 + i];
  }
  __syncthreads();
  const int col = blockIdx.x * 256 + tid;
  float a0=0,a1=0,a2=0,a3=0;
  const float* wp = Wo + (size_t)k0 * HID + col;
  #pragma unroll 4
  for (int i = 0; i < 128; ++i) {
    float w = wp[(size_t)i * HID];
    a0 += at_s[0][i] * w;
    a1 += at_s[1][i] * w;
    a2 += at_s[2][i] * w;
    a3 += at_s[3][i] * w;
  }
  atomicAdd(&out[0*HID + col], a0);
  atomicAdd(&out[1*HID + col], a1);
  atomicAdd(&out[2*HID + col], a2);
  atomicAdd(&out[3*HID + col], a3);
}

// ---------------- K9: cache copy (rows 0..4095) ------------------------------
__global__ __launch_bounds__(256)
void k_copy(const float4* __restrict__ src_ckv,
            const float4* __restrict__ src_kr,
            float4* __restrict__ dst_ckv,
            float4* __restrict__ dst_kr) {
  size_t id = (size_t)blockIdx.x * 256 + threadIdx.x;
  const size_t n1 = (size_t)NB * SS * CKV / 4;  // 2097152
  if (id < n1) {
    size_t b = id / (SS*CKV/4);
    size_t r = id % (SS*CKV/4);
    dst_ckv[b * ((size_t)SK*CKV/4) + r] = src_ckv[id];
  } else {
    size_t id2 = id - n1;
    size_t b = id2 / (SS*RD/4);
    size_t r = id2 % (SS*RD/4);
    dst_kr[b * ((size_t)SK*RD/4) + r] = src_kr[id2];
  }
}

extern "C" void kernel_launch(void* const* d_in, const int* in_sizes, int n_in,
                              void* d_out, int out_size, void* d_ws, size_t ws_size,
                              hipStream_t stream) {
  (void)in_sizes; (void)n_in; (void)out_size; (void)ws_size;
  const float* hidden = (const float*)d_in[0];
  const float* mask   = (const float*)d_in[1];
  const float* ckv_c  = (const float*)d_in[2];
  const float* kr_c   = (const float*)d_in[3];
  const float* Wdkv   = (const float*)d_in[4];
  const float* Wuk    = (const float*)d_in[5];
  const float* Wuv    = (const float*)d_in[6];
  const float* Wdq    = (const float*)d_in[7];
  const float* Wuq    = (const float*)d_in[8];
  const float* Wqr    = (const float*)d_in[9];
  const float* Wkr    = (const float*)d_in[10];
  const float* Wo     = (const float*)d_in[11];
  float* out = (float*)d_out;
  float* ws  = (float*)d_ws;
  float* out_ckv = out + NB*HID;                            // 16384
  float* out_kr  = out + NB*HID + (size_t)NB*SK*CKV;        // 16384 + 8390656

  hipMemsetAsync(ws, 0, (size_t)WS_ZERO_N * sizeof(float), stream);
  hipMemsetAsync(out, 0, (size_t)NB * HID * sizeof(float), stream);

  k_proj1<<<dim3(9, 32), 256, 0, stream>>>(hidden, Wdkv, Wdq, Wkr, ws);
  k_proj2<<<dim3(24, 12), 256, 0, stream>>>(Wuq, Wqr, ws);
  k_absorb_rope<<<129, 256, 0, stream>>>(Wuk, ws, out_ckv, out_kr);
  size_t sm_scores = (size_t)(NH*QAB_STRIDE + NH*QR_STRIDE) * sizeof(float);
  k_scores<<<dim3(33, 4), 256, sm_scores, stream>>>(ckv_c, kr_c, mask, ws);
  k_softmax<<<NB*NH, 256, 0, stream>>>(ws);
  k_pv<<<dim3(33, 4), 256, 0, stream>>>(ckv_c, ws);
  k_uv<<<dim3(16, 8), 256, 0, stream>>>(Wuv, ws);
  k_wo<<<dim3(16, 32), 256, 0, stream>>>(Wo, ws, out);
  k_copy<<<9216, 256, 0, stream>>>((const float4*)ckv_c, (const float4*)kr_c,
                                   (float4*)out_ckv, (float4*)out_kr);
}

// Round 2
// 177.777 us; speedup vs baseline: 2.0160x; 2.0160x over previous
//
#include <hip/hip_runtime.h>
#include <math.h>

#define NB 4
#define HID 4096
#define CKV 512
#define CQ 1536
#define NH 32
#define HD 128
#define RD 64
#define SS 4096
#define SK 4097

#define SCALE_F 0.07216878364870322f  // 1/sqrt(192)

// workspace offsets (floats) — everything below WS_ZERO_N is memset to 0
enum : int {
  WS_CKV    = 0,                       // [NB][CKV]      (zeroed, atomic)
  WS_CQ     = WS_CKV + NB*CKV,         // [NB][CQ]       (zeroed, atomic)
  WS_KRRAW  = WS_CQ + NB*CQ,           // [NB][RD]       (zeroed, atomic)
  WS_QC     = WS_KRRAW + NB*RD,        // [NB][HID]      (zeroed, atomic)
  WS_QRRAW  = WS_QC + NB*HID,          // [NB][NH*RD]    (zeroed, atomic)
  WS_OLAT   = WS_QRRAW + NB*NH*RD,     // [NB][NH][CKV]  (zeroed, atomic)
  WS_ATTN   = WS_OLAT + NB*NH*CKV,     // [NB][HID]      (zeroed, atomic)
  WS_SCORES = WS_ATTN + NB*HID,        // [NB][NH][SK]   (zeroed, atomic)
  WS_ZERO_N = WS_SCORES + NB*NH*SK,    // = 639360
  WS_QABS   = WS_ZERO_N,               // [NB][NH][CKV]  (pre-scaled by SCALE_F)
  WS_QROPE  = WS_QABS + NB*NH*CKV,     // [NB][NH][RD]   (pre-scaled by SCALE_F)
  WS_KROPE  = WS_QROPE + NB*NH*RD,     // [NB][RD]       (unscaled)
  WS_TOTAL  = WS_KROPE + NB*RD         // 713344 floats = 2.85 MB
};

__device__ inline void fma4(float4& a, float s, const float4& v) {
  a.x += s*v.x; a.y += s*v.y; a.z += s*v.z; a.w += s*v.w;
}

// ---------------- K1: hidden -> c_KV, c_Q, k_R_raw (K-split 32, atomics) ---
__global__ __launch_bounds__(256)
void k_proj1(const float* __restrict__ hidden,
             const float* __restrict__ Wdkv,
             const float* __restrict__ Wdq,
             const float* __restrict__ Wkr,
             float* __restrict__ ws) {
  __shared__ float hid_s[NB][128];
  const int tid = threadIdx.x;
  const int k0 = blockIdx.y * 128;
  for (int e = tid; e < NB*128; e += 256) {
    int b = e >> 7, i = e & 127;
    hid_s[b][i] = hidden[b*HID + k0 + i];
  }
  __syncthreads();
  const int col = blockIdx.x * 256 + tid;
  const float* W; int C; float* dst; int wcol;
  if (col < 512)       { W = Wdkv; C = CKV; wcol = col;        dst = ws + WS_CKV; }
  else if (col < 2048) { W = Wdq;  C = CQ;  wcol = col - 512;  dst = ws + WS_CQ; }
  else if (col < 2112) { W = Wkr;  C = RD;  wcol = col - 2048; dst = ws + WS_KRRAW; }
  else return;
  float a0=0,a1=0,a2=0,a3=0;
  const float* wp = W + (size_t)k0 * C + wcol;
  #pragma unroll 4
  for (int i = 0; i < 128; ++i) {
    float w = wp[(size_t)i * C];
    a0 += hid_s[0][i] * w;
    a1 += hid_s[1][i] * w;
    a2 += hid_s[2][i] * w;
    a3 += hid_s[3][i] * w;
  }
  atomicAdd(&dst[0*C + wcol], a0);
  atomicAdd(&dst[1*C + wcol], a1);
  atomicAdd(&dst[2*C + wcol], a2);
  atomicAdd(&dst[3*C + wcol], a3);
}

// ---------------- K2: c_Q -> q_C, q_R_raw (K-split 12, atomics) ------------
__global__ __launch_bounds__(256)
void k_proj2(const float* __restrict__ Wuq,
             const float* __restrict__ Wqr,
             float* __restrict__ ws) {
  __shared__ float cq_s[NB][128];
  const int tid = threadIdx.x;
  const int k0 = blockIdx.y * 128;
  for (int e = tid; e < NB*128; e += 256) {
    int b = e >> 7, i = e & 127;
    cq_s[b][i] = ws[WS_CQ + b*CQ + k0 + i];
  }
  __syncthreads();
  const int col = blockIdx.x * 256 + tid;  // < 6144 always
  const float* W; int C; float* dst; int wcol;
  if (col < 4096) { W = Wuq; C = NH*HD; wcol = col;        dst = ws + WS_QC; }
  else            { W = Wqr; C = NH*RD; wcol = col - 4096; dst = ws + WS_QRRAW; }
  float a0=0,a1=0,a2=0,a3=0;
  const float* wp = W + (size_t)k0 * C + wcol;
  #pragma unroll 4
  for (int i = 0; i < 128; ++i) {
    float w = wp[(size_t)i * C];
    a0 += cq_s[0][i] * w;
    a1 += cq_s[1][i] * w;
    a2 += cq_s[2][i] * w;
    a3 += cq_s[3][i] * w;
  }
  atomicAdd(&dst[0*C + wcol], a0);
  atomicAdd(&dst[1*C + wcol], a1);
  atomicAdd(&dst[2*C + wcol], a2);
  atomicAdd(&dst[3*C + wcol], a3);
}

// -------- K3: q_abs = q_C @ W_UK^T per head (×SCALE); RoPE; new cache rows --
__global__ __launch_bounds__(256)
void k_absorb_rope(const float* __restrict__ Wuk,
                   float* __restrict__ ws,
                   float* __restrict__ out_ckv,
                   float* __restrict__ out_kr) {
  const int bid = blockIdx.x, tid = threadIdx.x;
  if (bid < 128) {
    const int h = bid >> 2, cq = bid & 3;
    __shared__ float qc_s[NB][HD];
    __shared__ float part_s[NB][256];
    for (int e = tid; e < NB*HD; e += 256) {
      int b = e >> 7, d = e & 127;
      qc_s[b][d] = ws[WS_QC + b*HID + h*HD + d];
    }
    __syncthreads();
    const int c = cq*128 + (tid & 127);
    const int dh = (tid >> 7) * 64;
    const float4* wrow = (const float4*)(Wuk + (size_t)c*(NH*HD) + h*HD + dh);
    float acc[NB] = {0,0,0,0};
    #pragma unroll
    for (int d4 = 0; d4 < 16; ++d4) {
      float4 w4 = wrow[d4];
      #pragma unroll
      for (int b = 0; b < NB; ++b) {
        float4 q4 = *(const float4*)&qc_s[b][dh + d4*4];
        acc[b] += w4.x*q4.x + w4.y*q4.y + w4.z*q4.z + w4.w*q4.w;
      }
    }
    #pragma unroll
    for (int b = 0; b < NB; ++b) part_s[b][tid] = acc[b];
    __syncthreads();
    if (tid < 128) {
      #pragma unroll
      for (int b = 0; b < NB; ++b) {
        float v = part_s[b][tid] + part_s[b][tid + 128];
        ws[WS_QABS + (b*NH + h)*CKV + c] = v * SCALE_F;
      }
    }
  } else {
    const double LN1E4 = 9.210340371976184;  // ln(10000)
    // q_R rope (pre-scaled): NB*NH*32 pairs
    for (int pid = tid; pid < NB*NH*32; pid += 256) {
      int b = pid >> 10, rem = pid & 1023, h = rem >> 5, i = rem & 31;
      double ang = 4096.0 * exp(-(double)i / 32.0 * LN1E4);
      float cs = (float)cos(ang), sn = (float)sin(ang);
      float x1 = ws[WS_QRRAW + b*(NH*RD) + h*RD + 2*i];
      float x2 = ws[WS_QRRAW + b*(NH*RD) + h*RD + 2*i + 1];
      ws[WS_QROPE + (b*NH + h)*RD + 2*i]     = (x1*cs - x2*sn) * SCALE_F;
      ws[WS_QROPE + (b*NH + h)*RD + 2*i + 1] = (x1*sn + x2*cs) * SCALE_F;
    }
    // k_R rope (unscaled) + new k_R cache row
    if (tid < NB*32) {
      int b = tid >> 5, i = tid & 31;
      double ang = 4096.0 * exp(-(double)i / 32.0 * LN1E4);
      float cs = (float)cos(ang), sn = (float)sin(ang);
      float x1 = ws[WS_KRRAW + b*RD + 2*i];
      float x2 = ws[WS_KRRAW + b*RD + 2*i + 1];
      float o0 = x1*cs - x2*sn, o1 = x1*sn + x2*cs;
      ws[WS_KROPE + b*RD + 2*i]     = o0;
      ws[WS_KROPE + b*RD + 2*i + 1] = o1;
      out_kr[(size_t)b*SK*RD + (size_t)SS*RD + 2*i]     = o0;
      out_kr[(size_t)b*SK*RD + (size_t)SS*RD + 2*i + 1] = o1;
    }
    // new c_KV cache row
    for (int e = tid; e < NB*CKV; e += 256) {
      int b = e >> 9, cc = e & 511;
      out_ckv[(size_t)b*SK*CKV + (size_t)SS*CKV + cc] = ws[WS_CKV + b*CKV + cc];
    }
  }
}

// ---------------- K4: scores = q_abs·c_KV^T + q_R·k_R^T (tiled GEMM) -------
// block: 128 keys x 32 heads x half-of-c; grid (33, 2, 4); atomics into
// pre-zeroed WS_SCORES. q pre-scaled, mask applied in softmax.
__global__ __launch_bounds__(256)
void k_scores(const float* __restrict__ kv_cache,
              const float* __restrict__ kr_cache,
              float* __restrict__ ws) {
  __shared__ float kv_s[128*68];
  __shared__ float q_s[32*68];
  const int tid = threadIdx.x;
  const int k0 = blockIdx.x * 128;
  const int cs = blockIdx.y;
  const int b  = blockIdx.z;
  const int kg = tid & 31, hg = tid >> 5;
  float acc[4][4];
  #pragma unroll
  for (int i=0;i<4;++i)
    #pragma unroll
    for (int j=0;j<4;++j) acc[i][j]=0.f;
  const int cc_lo = cs ? 4 : 0, cc_hi = cs ? 9 : 4;
  for (int cc = cc_lo; cc < cc_hi; ++cc) {
    const int f4 = tid & 15;
    // stage kv chunk: 128 rows x 64 floats
    #pragma unroll
    for (int i = 0; i < 8; ++i) {
      int row = (tid >> 4) + 16*i;
      int k = k0 + row;
      float4 v = make_float4(0,0,0,0);
      if (cc < 8) {
        if (k < SS)       v = *(const float4*)(kv_cache + ((size_t)b*SS + k)*CKV + cc*64 + f4*4);
        else if (k == SS) v = *(const float4*)(ws + WS_CKV + b*CKV + cc*64 + f4*4);
      } else {
        if (k < SS)       v = *(const float4*)(kr_cache + ((size_t)b*SS + k)*RD + f4*4);
        else if (k == SS) v = *(const float4*)(ws + WS_KROPE + b*RD + f4*4);
      }
      *(float4*)&kv_s[row*68 + f4*4] = v;
    }
    // stage q chunk: 32 heads x 64 floats
    #pragma unroll
    for (int i = 0; i < 2; ++i) {
      int h = (tid >> 4) + 16*i;
      float4 v;
      if (cc < 8) v = *(const float4*)(ws + WS_QABS + (size_t)(b*NH + h)*CKV + cc*64 + f4*4);
      else        v = *(const float4*)(ws + WS_QROPE + (size_t)(b*NH + h)*RD + f4*4);
      *(float4*)&q_s[h*68 + f4*4] = v;
    }
    __syncthreads();
    #pragma unroll 4
    for (int c4 = 0; c4 < 16; ++c4) {
      float4 q4[4], kv4[4];
      #pragma unroll
      for (int j=0;j<4;++j) q4[j] = *(const float4*)&q_s[(hg+8*j)*68 + c4*4];
      #pragma unroll
      for (int i=0;i<4;++i) kv4[i] = *(const float4*)&kv_s[(kg+32*i)*68 + c4*4];
      #pragma unroll
      for (int i=0;i<4;++i)
        #pragma unroll
        for (int j=0;j<4;++j)
          acc[i][j] += kv4[i].x*q4[j].x + kv4[i].y*q4[j].y
                     + kv4[i].z*q4[j].z + kv4[i].w*q4[j].w;
    }
    __syncthreads();
  }
  #pragma unroll
  for (int i=0;i<4;++i) {
    int k = k0 + kg + 32*i;
    if (k < SK) {
      #pragma unroll
      for (int j=0;j<4;++j)
        atomicAdd(ws + WS_SCORES + (size_t)(b*NH + hg + 8*j)*SK + k, acc[i][j]);
    }
  }
}

// ---------------- K5: row softmax over SK=4097 (applies mask) ---------------
__global__ __launch_bounds__(256)
void k_softmax(const float* __restrict__ mask, float* __restrict__ ws) {
  __shared__ float red[256];
  const int tid = threadIdx.x;
  const int b = blockIdx.x >> 5;
  float* s = ws + WS_SCORES + (size_t)blockIdx.x * SK;
  const float* mrow = mask + (size_t)b * SK;
  float v[17];
  float m = -INFINITY;
  #pragma unroll
  for (int r = 0; r < 17; ++r) {
    int k = tid + r*256;
    v[r] = (k < SK) ? (s[k] + mrow[k] * (-1e9f)) : -INFINITY;
    m = fmaxf(m, v[r]);
  }
  red[tid] = m; __syncthreads();
  for (int st = 128; st > 0; st >>= 1) {
    if (tid < st) red[tid] = fmaxf(red[tid], red[tid+st]);
    __syncthreads();
  }
  m = red[0]; __syncthreads();
  float e[17];
  float l = 0.f;
  #pragma unroll
  for (int r = 0; r < 17; ++r) {
    int k = tid + r*256;
    e[r] = (k < SK) ? __expf(v[r] - m) : 0.f;
    l += e[r];
  }
  red[tid] = l; __syncthreads();
  for (int st = 128; st > 0; st >>= 1) {
    if (tid < st) red[tid] += red[tid+st];
    __syncthreads();
  }
  float inv = 1.f / red[0];
  #pragma unroll
  for (int r = 0; r < 17; ++r) {
    int k = tid + r*256;
    if (k < SK) s[k] = e[r] * inv;
  }
}

// ---------------- K6: o_latent = probs @ c_KV (tiled GEMM, k-split) --------
// block: 256 keys x 32 heads x 128 c; grid (17, 4, 4); atomics into WS_OLAT.
__global__ __launch_bounds__(256)
void k_pv(const float* __restrict__ kv_cache, float* __restrict__ ws) {
  __shared__ float kv_s[64*132];
  __shared__ float p_s[32*68];
  const int tid = threadIdx.x;
  const int kbase = blockIdx.x * 256;
  const int c0 = blockIdx.y * 128;
  const int b  = blockIdx.z;
  const int cg = tid & 31, hg = tid >> 5;
  float4 acc[4];
  #pragma unroll
  for (int j=0;j<4;++j) acc[j] = make_float4(0,0,0,0);
  for (int ch = 0; ch < 4; ++ch) {
    const int k0 = kbase + ch*64;
    // stage p: 32 heads x 64 keys (scalar, guarded)
    {
      int h = tid >> 3, i0 = (tid & 7) * 8;
      const float* srow = ws + WS_SCORES + (size_t)(b*NH + h)*SK;
      #pragma unroll
      for (int e = 0; e < 8; ++e) {
        int k = k0 + i0 + e;
        p_s[h*68 + i0 + e] = (k < SK) ? srow[k] : 0.f;
      }
    }
    // stage kv: 64 rows x 128 floats (this block's c-window)
    {
      int q = tid & 7;
      #pragma unroll
      for (int i = 0; i < 2; ++i) {
        int row = (tid >> 3) + 32*i;
        int k = k0 + row;
        const float* src = (k < SS)  ? (kv_cache + ((size_t)b*SS + k)*CKV + c0)
                         : (k == SS) ? (ws + WS_CKV + b*CKV + c0) : nullptr;
        #pragma unroll
        for (int j = 0; j < 4; ++j) {
          float4 v = src ? *(const float4*)(src + q*16 + j*4) : make_float4(0,0,0,0);
          *(float4*)&kv_s[row*132 + q*16 + j*4] = v;
        }
      }
    }
    __syncthreads();
    #pragma unroll 2
    for (int k4 = 0; k4 < 16; ++k4) {
      float4 p4[4], kv4[4];
      #pragma unroll
      for (int j=0;j<4;++j) p4[j] = *(const float4*)&p_s[(hg+8*j)*68 + k4*4];
      #pragma unroll
      for (int i=0;i<4;++i) kv4[i] = *(const float4*)&kv_s[(k4*4+i)*132 + cg*4];
      #pragma unroll
      for (int j=0;j<4;++j) {
        fma4(acc[j], p4[j].x, kv4[0]);
        fma4(acc[j], p4[j].y, kv4[1]);
        fma4(acc[j], p4[j].z, kv4[2]);
        fma4(acc[j], p4[j].w, kv4[3]);
      }
    }
    __syncthreads();
  }
  #pragma unroll
  for (int j=0;j<4;++j) {
    float* dst = ws + WS_OLAT + (size_t)(b*NH + hg + 8*j)*CKV + c0 + cg*4;
    atomicAdd(dst+0, acc[j].x);
    atomicAdd(dst+1, acc[j].y);
    atomicAdd(dst+2, acc[j].z);
    atomicAdd(dst+3, acc[j].w);
  }
}

// ---------------- K7: attn = o_latent @ W_UV (per head) ---------------------
__global__ __launch_bounds__(256)
void k_uv(const float* __restrict__ Wuv, float* __restrict__ ws) {
  __shared__ float ol_s[2][NB][64];
  const int tid = threadIdx.x;
  const int c0 = blockIdx.y * 64;
  const int colbase = blockIdx.x * 256;
  for (int e = tid; e < 2*NB*64; e += 256) {
    int hh = e >> 8, rem = e & 255, b = rem >> 6, cc = rem & 63;
    int h = (colbase >> 7) + hh;
    ol_s[hh][b][cc] = ws[WS_OLAT + (size_t)(b*NH + h)*CKV + c0 + cc];
  }
  __syncthreads();
  const int col = colbase + tid;
  const int hh = tid >> 7;
  float a0=0,a1=0,a2=0,a3=0;
  const float* wp = Wuv + (size_t)c0 * (NH*HD) + col;
  #pragma unroll 4
  for (int cc = 0; cc < 64; ++cc) {
    float w = wp[(size_t)cc * (NH*HD)];
    a0 += ol_s[hh][0][cc] * w;
    a1 += ol_s[hh][1][cc] * w;
    a2 += ol_s[hh][2][cc] * w;
    a3 += ol_s[hh][3][cc] * w;
  }
  atomicAdd(&ws[WS_ATTN + 0*HID + col], a0);
  atomicAdd(&ws[WS_ATTN + 1*HID + col], a1);
  atomicAdd(&ws[WS_ATTN + 2*HID + col], a2);
  atomicAdd(&ws[WS_ATTN + 3*HID + col], a3);
}

// ---------------- K8: out = attn @ W_O (K-split 32, atomics into d_out) -----
__global__ __launch_bounds__(256)
void k_wo(const float* __restrict__ Wo, const float* __restrict__ ws,
          float* __restrict__ out) {
  __shared__ float at_s[NB][128];
  const int tid = threadIdx.x;
  const int k0 = blockIdx.y * 128;
  for (int e = tid; e < NB*128; e += 256) {
    int b = e >> 7, i = e & 127;
    at_s[b][i] = ws[WS_ATTN + b*HID + k0 + i];
  }
  __syncthreads();
  const int col = blockIdx.x * 256 + tid;
  float a0=0,a1=0,a2=0,a3=0;
  const float* wp = Wo + (size_t)k0 * HID + col;
  #pragma unroll 4
  for (int i = 0; i < 128; ++i) {
    float w = wp[(size_t)i * HID];
    a0 += at_s[0][i] * w;
    a1 += at_s[1][i] * w;
    a2 += at_s[2][i] * w;
    a3 += at_s[3][i] * w;
  }
  atomicAdd(&out[0*HID + col], a0);
  atomicAdd(&out[1*HID + col], a1);
  atomicAdd(&out[2*HID + col], a2);
  atomicAdd(&out[3*HID + col], a3);
}

// ---------------- K9: cache copy (rows 0..4095) ------------------------------
__global__ __launch_bounds__(256)
void k_copy(const float4* __restrict__ src_ckv,
            const float4* __restrict__ src_kr,
            float4* __restrict__ dst_ckv,
            float4* __restrict__ dst_kr) {
  size_t id = (size_t)blockIdx.x * 256 + threadIdx.x;
  const size_t n1 = (size_t)NB * SS * CKV / 4;  // 2097152
  if (id < n1) {
    size_t b = id / (SS*CKV/4);
    size_t r = id % (SS*CKV/4);
    dst_ckv[b * ((size_t)SK*CKV/4) + r] = src_ckv[id];
  } else {
    size_t id2 = id - n1;
    size_t b = id2 / (SS*RD/4);
    size_t r = id2 % (SS*RD/4);
    dst_kr[b * ((size_t)SK*RD/4) + r] = src_kr[id2];
  }
}

extern "C" void kernel_launch(void* const* d_in, const int* in_sizes, int n_in,
                              void* d_out, int out_size, void* d_ws, size_t ws_size,
                              hipStream_t stream) {
  (void)in_sizes; (void)n_in; (void)out_size; (void)ws_size;
  const float* hidden = (const float*)d_in[0];
  const float* mask   = (const float*)d_in[1];
  const float* ckv_c  = (const float*)d_in[2];
  const float* kr_c   = (const float*)d_in[3];
  const float* Wdkv   = (const float*)d_in[4];
  const float* Wuk    = (const float*)d_in[5];
  const float* Wuv    = (const float*)d_in[6];
  const float* Wdq    = (const float*)d_in[7];
  const float* Wuq    = (const float*)d_in[8];
  const float* Wqr    = (const float*)d_in[9];
  const float* Wkr    = (const float*)d_in[10];
  const float* Wo     = (const float*)d_in[11];
  float* out = (float*)d_out;
  float* ws  = (float*)d_ws;
  float* out_ckv = out + NB*HID;                            // 16384
  float* out_kr  = out + NB*HID + (size_t)NB*SK*CKV;        // 16384 + 8390656

  hipMemsetAsync(ws, 0, (size_t)WS_ZERO_N * sizeof(float), stream);
  hipMemsetAsync(out, 0, (size_t)NB * HID * sizeof(float), stream);

  k_proj1<<<dim3(9, 32), 256, 0, stream>>>(hidden, Wdkv, Wdq, Wkr, ws);
  k_proj2<<<dim3(24, 12), 256, 0, stream>>>(Wuq, Wqr, ws);
  k_absorb_rope<<<129, 256, 0, stream>>>(Wuk, ws, out_ckv, out_kr);
  k_scores<<<dim3(33, 2, 4), 256, 0, stream>>>(ckv_c, kr_c, ws);
  k_softmax<<<NB*NH, 256, 0, stream>>>(mask, ws);
  k_pv<<<dim3(17, 4, 4), 256, 0, stream>>>(ckv_c, ws);
  k_uv<<<dim3(16, 8), 256, 0, stream>>>(Wuv, ws);
  k_wo<<<dim3(16, 32), 256, 0, stream>>>(Wo, ws, out);
  k_copy<<<9216, 256, 0, stream>>>((const float4*)ckv_c, (const float4*)kr_c,
                                   (float4*)out_ckv, (float4*)out_kr);
}